// Round 1
// baseline (688.521 us; speedup 1.0000x reference)
//
#include <hip/hip_runtime.h>

#define Bc 16
#define Cc 512
#define Tc 2048
#define QT 64
#define KT 64
#define PST 72   // P_lds row stride (ushort), 64+8 pad

typedef __attribute__((ext_vector_type(8))) short short8;
typedef __attribute__((ext_vector_type(4))) float f32x4;
typedef unsigned short u16;

static __device__ __forceinline__ u16 f2bf(float x) {
  unsigned u = __float_as_uint(x);
  u += 0x7FFF + ((u >> 16) & 1);   // RNE
  return (u16)(u >> 16);
}

// ---------------- Kernel 1: kqT[b][t][ch]  ch 0..63 = k, 64..127 = q (bf16) ----------------
__global__ __launch_bounds__(256) void kq_kernel(
    const float* __restrict__ v, const float* __restrict__ Wk, const float* __restrict__ bk,
    const float* __restrict__ Wq, const float* __restrict__ bq, u16* __restrict__ kq)
{
  __shared__ float lv[64][64];
  const int b  = blockIdx.y;
  const int t0 = blockIdx.x * 64;
  const int tid = threadIdx.x;
  const int t  = tid & 63;
  int kg = __builtin_amdgcn_readfirstlane(tid >> 6);   // 0..3, wave-uniform

  const float* wbase = (kg < 2) ? (Wk + (size_t)kg * 32 * Cc)
                                : (Wq + (size_t)(kg - 2) * 32 * Cc);
  float acc[32];
  #pragma unroll
  for (int o = 0; o < 32; ++o) acc[o] = 0.f;

  const float* vb = v + (size_t)b * Cc * Tc + t0;
  for (int c0 = 0; c0 < Cc; c0 += 64) {
    __syncthreads();
    #pragma unroll
    for (int r = 0; r < 16; ++r) {
      int row = r * 4 + kg;
      lv[row][t] = vb[(size_t)(c0 + row) * Tc + t];
    }
    __syncthreads();
    #pragma unroll
    for (int cc = 0; cc < 64; cc += 16) {
      float vv[16];
      #pragma unroll
      for (int i = 0; i < 16; ++i) vv[i] = lv[cc + i][t];
      #pragma unroll
      for (int o = 0; o < 32; ++o) {
        #pragma unroll
        for (int i = 0; i < 16; ++i)
          acc[o] = fmaf(wbase[o * Cc + c0 + cc + i], vv[i], acc[o]);
      }
    }
  }
  const float* bias = (kg < 2) ? (bk + kg * 32) : (bq + (kg - 2) * 32);
  u16* outp = kq + (size_t)(b * Tc + t0 + t) * 128 + kg * 32;
  #pragma unroll
  for (int o = 0; o < 32; ++o) outp[o] = f2bf(acc[o] + bias[o]);
}

// ---------------- Kernel 2: flash attention over i ----------------
// out[b,c,j] = v[b,c,j] + gamma * (sum_i exp(s_ij - m_j) v[b,c,i]) / l_j
__global__ __launch_bounds__(512) void attn_kernel(
    const float* __restrict__ v, const u16* __restrict__ kq,
    const float* __restrict__ gamma_p, float* __restrict__ out)
{
  __shared__ u16 P[64 * PST];
  __shared__ float scl_lds[64];
  __shared__ float lsum_lds[64];

  const int b   = blockIdx.y;
  const int j0  = blockIdx.x * QT;
  const int tid = threadIdx.x;
  const int lane = tid & 63;
  const int wid  = tid >> 6;      // 0..7
  const int l15  = lane & 15;
  const int lg   = lane >> 4;     // 0..3
  const int jt   = wid & 3;       // owned S j-tile
  const int ih   = wid >> 2;      // which half of i-tiles this wave writes
  const int c0   = wid * 64;      // O channel slice

  // Q B-fragments for owned jt: B[d][j], lane: j = l15, d = ds*32 + lg*8 + e
  short8 qf0, qf1;
  {
    const u16* qp = kq + (size_t)(b * Tc + j0 + jt * 16 + l15) * 128 + 64 + lg * 8;
    qf0 = *reinterpret_cast<const short8*>(qp);
    qf1 = *reinterpret_cast<const short8*>(qp + 32);
  }

  f32x4 O[4][4];
  #pragma unroll
  for (int a = 0; a < 4; ++a)
    #pragma unroll
    for (int bb = 0; bb < 4; ++bb) O[a][bb] = f32x4{0.f, 0.f, 0.f, 0.f};

  float m = -1e30f, lsum = 0.f;

  for (int i0 = 0; i0 < Tc; i0 += KT) {
    // ---- S tile for owned jt: sacc[it] = k^T q  (16 i x 16 j each) ----
    f32x4 sacc[4];
    const u16* kp = kq + (size_t)(b * Tc + i0 + l15) * 128 + lg * 8;
    #pragma unroll
    for (int it = 0; it < 4; ++it) {
      short8 af0 = *reinterpret_cast<const short8*>(kp + (size_t)it * 16 * 128);
      short8 af1 = *reinterpret_cast<const short8*>(kp + (size_t)it * 16 * 128 + 32);
      f32x4 s = f32x4{0.f, 0.f, 0.f, 0.f};
      s = __builtin_amdgcn_mfma_f32_16x16x32_bf16(af0, qf0, s, 0, 0, 0);
      s = __builtin_amdgcn_mfma_f32_16x16x32_bf16(af1, qf1, s, 0, 0, 0);
      sacc[it] = s;
    }

    // ---- online softmax over i (lane holds 16 i-values of one j) ----
    float tmax = -1e30f;
    #pragma unroll
    for (int it = 0; it < 4; ++it)
      #pragma unroll
      for (int r = 0; r < 4; ++r) tmax = fmaxf(tmax, sacc[it][r]);
    tmax = fmaxf(tmax, __shfl_xor(tmax, 16));
    tmax = fmaxf(tmax, __shfl_xor(tmax, 32));
    float mnew  = fmaxf(m, tmax);
    float scale = __expf(m - mnew);
    float psum = 0.f;
    u16 pb[4][4];
    #pragma unroll
    for (int it = 0; it < 4; ++it)
      #pragma unroll
      for (int r = 0; r < 4; ++r) {
        float p = __expf(sacc[it][r] - mnew);
        psum += p;
        pb[it][r] = f2bf(p);
      }
    psum += __shfl_xor(psum, 16);
    psum += __shfl_xor(psum, 32);
    lsum = lsum * scale + psum;
    m = mnew;

    // ---- write P transposed [j][i] (bf16), split i-halves across wave pairs ----
    if (ih == 0) {
      uint2 w0, w1;
      w0.x = (unsigned)pb[0][0] | ((unsigned)pb[0][1] << 16);
      w0.y = (unsigned)pb[0][2] | ((unsigned)pb[0][3] << 16);
      w1.x = (unsigned)pb[1][0] | ((unsigned)pb[1][1] << 16);
      w1.y = (unsigned)pb[1][2] | ((unsigned)pb[1][3] << 16);
      *reinterpret_cast<uint2*>(&P[(jt * 16 + l15) * PST + 0 * 16 + lg * 4]) = w0;
      *reinterpret_cast<uint2*>(&P[(jt * 16 + l15) * PST + 1 * 16 + lg * 4]) = w1;
    } else {
      uint2 w2, w3;
      w2.x = (unsigned)pb[2][0] | ((unsigned)pb[2][1] << 16);
      w2.y = (unsigned)pb[2][2] | ((unsigned)pb[2][3] << 16);
      w3.x = (unsigned)pb[3][0] | ((unsigned)pb[3][1] << 16);
      w3.y = (unsigned)pb[3][2] | ((unsigned)pb[3][3] << 16);
      *reinterpret_cast<uint2*>(&P[(jt * 16 + l15) * PST + 2 * 16 + lg * 4]) = w2;
      *reinterpret_cast<uint2*>(&P[(jt * 16 + l15) * PST + 3 * 16 + lg * 4]) = w3;
    }
    if (wid < 4 && lane < 16) scl_lds[jt * 16 + lane] = scale;
    __syncthreads();

    // ---- rescale O by per-j scale ----
    float sc[4];
    #pragma unroll
    for (int jj = 0; jj < 4; ++jj) sc[jj] = scl_lds[jj * 16 + l15];
    #pragma unroll
    for (int ct = 0; ct < 4; ++ct)
      #pragma unroll
      for (int jj = 0; jj < 4; ++jj)
        #pragma unroll
        for (int r = 0; r < 4; ++r) O[ct][jj][r] *= sc[jj];

    // ---- PV: O[c,j] += V[c,i] P[i,j] ----
    #pragma unroll
    for (int is = 0; is < 2; ++is) {
      short8 pf[4];
      #pragma unroll
      for (int jj = 0; jj < 4; ++jj)
        pf[jj] = *reinterpret_cast<const short8*>(&P[(jj * 16 + l15) * PST + is * 32 + lg * 8]);
      #pragma unroll
      for (int ct = 0; ct < 4; ++ct) {
        const float* vp = v + (size_t)(b * Cc + c0 + ct * 16 + l15) * Tc + i0 + is * 32 + lg * 8;
        f32x4 v0 = *reinterpret_cast<const f32x4*>(vp);
        f32x4 v1 = *reinterpret_cast<const f32x4*>(vp + 4);
        short8 af;
        af[0] = (short)f2bf(v0[0]); af[1] = (short)f2bf(v0[1]);
        af[2] = (short)f2bf(v0[2]); af[3] = (short)f2bf(v0[3]);
        af[4] = (short)f2bf(v1[0]); af[5] = (short)f2bf(v1[1]);
        af[6] = (short)f2bf(v1[2]); af[7] = (short)f2bf(v1[3]);
        #pragma unroll
        for (int jj = 0; jj < 4; ++jj)
          O[ct][jj] = __builtin_amdgcn_mfma_f32_16x16x32_bf16(af, pf[jj], O[ct][jj], 0, 0, 0);
      }
    }
    __syncthreads();
  }

  if (wid < 4 && lane < 16) lsum_lds[jt * 16 + lane] = lsum;
  __syncthreads();
  const float gamma = *gamma_p;
  #pragma unroll
  for (int jj = 0; jj < 4; ++jj) {
    float linv = gamma / lsum_lds[jj * 16 + l15];
    int j = j0 + jj * 16 + l15;
    #pragma unroll
    for (int ct = 0; ct < 4; ++ct) {
      #pragma unroll
      for (int r = 0; r < 4; ++r) {
        int c = c0 + ct * 16 + lg * 4 + r;
        size_t idx = (size_t)(b * Cc + c) * Tc + j;
        out[idx] = v[idx] + linv * O[ct][jj][r];
      }
    }
  }
}

extern "C" void kernel_launch(void* const* d_in, const int* in_sizes, int n_in,
                              void* d_out, int out_size, void* d_ws, size_t ws_size,
                              hipStream_t stream) {
  const float* v  = (const float*)d_in[0];
  const float* Wk = (const float*)d_in[1];
  const float* bk = (const float*)d_in[2];
  const float* Wq = (const float*)d_in[3];
  const float* bq = (const float*)d_in[4];
  const float* gm = (const float*)d_in[5];
  float* out = (float*)d_out;
  u16* kq = (u16*)d_ws;   // B*T*128 bf16 = 8.4 MB

  dim3 g1(Tc / 64, Bc), b1(256);
  kq_kernel<<<g1, b1, 0, stream>>>(v, Wk, bk, Wq, bq, kq);
  dim3 g2(Tc / QT, Bc), b2(512);
  attn_kernel<<<g2, b2, 0, stream>>>(v, kq, gm, out);
}

// Round 2
// 325.483 us; speedup vs baseline: 2.1154x; 2.1154x over previous
//
#include <hip/hip_runtime.h>

#define Bc 16
#define Cc 512
#define Tc 2048
#define QT 64
#define KT 64
#define PST 72   // P_lds row stride (ushort), 64+8 pad
#define LTS 66   // kqv LDS transposed-tile row stride (ushort), 64+2 pad

typedef __attribute__((ext_vector_type(8))) short short8;
typedef __attribute__((ext_vector_type(4))) float f32x4;
typedef unsigned short u16;

static __device__ __forceinline__ u16 f2bf(float x) {
  unsigned u = __float_as_uint(x);
  u += 0x7FFF + ((u >> 16) & 1);   // RNE
  return (u16)(u >> 16);
}

// ---------------- Kernel 0: W -> bf16 (fused k||q), bias -> bkq ----------------
__global__ __launch_bounds__(256) void prep_kernel(
    const float* __restrict__ Wk, const float* __restrict__ Wq,
    const float* __restrict__ bk, const float* __restrict__ bq,
    u16* __restrict__ Wbf, float* __restrict__ bkq)
{
  int idx  = blockIdx.x * 256 + threadIdx.x;
  int base = idx * 4;
  if (base < 128 * Cc) {
    int ch = base >> 9;
    int c  = base & (Cc - 1);
    const float* src = (ch < 64) ? (Wk + (size_t)ch * Cc + c)
                                 : (Wq + (size_t)(ch - 64) * Cc + c);
    f32x4 w = *reinterpret_cast<const f32x4*>(src);
    uint2 o;
    o.x = (unsigned)f2bf(w[0]) | ((unsigned)f2bf(w[1]) << 16);
    o.y = (unsigned)f2bf(w[2]) | ((unsigned)f2bf(w[3]) << 16);
    *reinterpret_cast<uint2*>(Wbf + base) = o;
  }
  if (idx < 128) bkq[idx] = (idx < 64) ? bk[idx] : bq[idx - 64];
}

// ---------------- Kernel 1: kq[t][ch] via MFMA + vbf16 emission ----------------
// D[ch][t] = sum_c W[ch][c] * v[c][t];  also vbf[b][c][t] = bf16(v)
__global__ __launch_bounds__(256) void kqv_kernel(
    const float* __restrict__ v, const u16* __restrict__ Wbf,
    const float* __restrict__ bkq, u16* __restrict__ kq, u16* __restrict__ vbf)
{
  __shared__ u16 LDSt[64][LTS];   // [t][c] transposed bf16 tile
  const int b   = blockIdx.y;
  const int t0  = blockIdx.x * 64;
  const int tid = threadIdx.x;
  const int lane = tid & 63;
  const int w    = tid >> 6;     // 0..3
  const int l15  = lane & 15;
  const int lg   = lane >> 4;

  f32x4 acc[8];
  #pragma unroll
  for (int mt = 0; mt < 8; ++mt) acc[mt] = f32x4{0.f, 0.f, 0.f, 0.f};

  const float* vb = v + (size_t)b * Cc * Tc + t0;
  for (int c0 = 0; c0 < Cc; c0 += 64) {
    __syncthreads();
    #pragma unroll
    for (int r = 0; r < 16; ++r) {
      int c = c0 + w * 16 + r;
      float x = vb[(size_t)c * Tc + lane];
      u16 hb = f2bf(x);
      LDSt[lane][w * 16 + r] = hb;
      vbf[((size_t)b * Cc + c) * Tc + t0 + lane] = hb;
    }
    __syncthreads();
    #pragma unroll
    for (int ks = 0; ks < 2; ++ks) {
      short8 bfrag = *reinterpret_cast<const short8*>(&LDSt[w * 16 + l15][ks * 32 + lg * 8]);
      #pragma unroll
      for (int mt = 0; mt < 8; ++mt) {
        short8 afrag = *reinterpret_cast<const short8*>(
            Wbf + (size_t)(mt * 16 + l15) * Cc + c0 + ks * 32 + lg * 8);
        acc[mt] = __builtin_amdgcn_mfma_f32_16x16x32_bf16(afrag, bfrag, acc[mt], 0, 0, 0);
      }
    }
  }
  const int t = t0 + w * 16 + l15;
  u16* op = kq + ((size_t)b * Tc + t) * 128;
  #pragma unroll
  for (int mt = 0; mt < 8; ++mt) {
    int chb = mt * 16 + lg * 4;
    float a0 = acc[mt][0] + bkq[chb + 0];
    float a1 = acc[mt][1] + bkq[chb + 1];
    float a2 = acc[mt][2] + bkq[chb + 2];
    float a3 = acc[mt][3] + bkq[chb + 3];
    uint2 o;
    o.x = (unsigned)f2bf(a0) | ((unsigned)f2bf(a1) << 16);
    o.y = (unsigned)f2bf(a2) | ((unsigned)f2bf(a3) << 16);
    *reinterpret_cast<uint2*>(op + chb) = o;
  }
}

// ---------------- Kernel 2: flash attention over i ----------------
__global__ __launch_bounds__(512) void attn_kernel(
    const float* __restrict__ v, const u16* __restrict__ vbf,
    const u16* __restrict__ kq, const float* __restrict__ gamma_p,
    float* __restrict__ out)
{
  __shared__ u16 P[64 * PST];
  __shared__ float scl_lds[64];
  __shared__ float lsum_lds[64];

  const int b   = blockIdx.y;
  const int j0  = blockIdx.x * QT;
  const int tid = threadIdx.x;
  const int lane = tid & 63;
  const int wid  = tid >> 6;      // 0..7
  const int l15  = lane & 15;
  const int lg   = lane >> 4;     // 0..3
  const int jt   = wid & 3;       // owned S j-tile
  const int ih   = wid >> 2;      // which half of i-tiles this wave writes
  const int c0   = wid * 64;      // O channel slice

  short8 qf0, qf1;
  {
    const u16* qp = kq + (size_t)(b * Tc + j0 + jt * 16 + l15) * 128 + 64 + lg * 8;
    qf0 = *reinterpret_cast<const short8*>(qp);
    qf1 = *reinterpret_cast<const short8*>(qp + 32);
  }

  f32x4 O[4][4];
  #pragma unroll
  for (int a = 0; a < 4; ++a)
    #pragma unroll
    for (int bb = 0; bb < 4; ++bb) O[a][bb] = f32x4{0.f, 0.f, 0.f, 0.f};

  float m = -1e30f, lsum = 0.f;

  for (int i0 = 0; i0 < Tc; i0 += KT) {
    // ---- prefetch V fragments (bf16) for this i-tile ----
    short8 vf[2][4];
    {
      const u16* vpb = vbf + ((size_t)b * Cc + c0) * Tc + i0;
      #pragma unroll
      for (int is = 0; is < 2; ++is)
        #pragma unroll
        for (int ct = 0; ct < 4; ++ct)
          vf[is][ct] = *reinterpret_cast<const short8*>(
              vpb + (size_t)(ct * 16 + l15) * Tc + is * 32 + lg * 8);
    }

    // ---- S tile for owned jt ----
    f32x4 sacc[4];
    const u16* kp = kq + (size_t)(b * Tc + i0 + l15) * 128 + lg * 8;
    #pragma unroll
    for (int it = 0; it < 4; ++it) {
      short8 af0 = *reinterpret_cast<const short8*>(kp + (size_t)it * 16 * 128);
      short8 af1 = *reinterpret_cast<const short8*>(kp + (size_t)it * 16 * 128 + 32);
      f32x4 s = f32x4{0.f, 0.f, 0.f, 0.f};
      s = __builtin_amdgcn_mfma_f32_16x16x32_bf16(af0, qf0, s, 0, 0, 0);
      s = __builtin_amdgcn_mfma_f32_16x16x32_bf16(af1, qf1, s, 0, 0, 0);
      sacc[it] = s;
    }

    // ---- online softmax over i with defer-max (THR=8) ----
    float tmax = -1e30f;
    #pragma unroll
    for (int it = 0; it < 4; ++it)
      #pragma unroll
      for (int r = 0; r < 4; ++r) tmax = fmaxf(tmax, sacc[it][r]);
    tmax = fmaxf(tmax, __shfl_xor(tmax, 16));
    tmax = fmaxf(tmax, __shfl_xor(tmax, 32));
    bool defer  = (tmax - m <= 8.f);
    float mnew  = defer ? m : tmax;
    float scale = defer ? 1.f : __expf(m - tmax);
    float psum = 0.f;
    u16 pb[4][4];
    #pragma unroll
    for (int it = 0; it < 4; ++it)
      #pragma unroll
      for (int r = 0; r < 4; ++r) {
        float p = __expf(sacc[it][r] - mnew);
        psum += p;
        pb[it][r] = f2bf(p);
      }
    psum += __shfl_xor(psum, 16);
    psum += __shfl_xor(psum, 32);
    lsum = lsum * scale + psum;
    m = mnew;

    // ---- write P transposed [j][i], split i-halves across wave pairs ----
    if (ih == 0) {
      uint2 w0, w1;
      w0.x = (unsigned)pb[0][0] | ((unsigned)pb[0][1] << 16);
      w0.y = (unsigned)pb[0][2] | ((unsigned)pb[0][3] << 16);
      w1.x = (unsigned)pb[1][0] | ((unsigned)pb[1][1] << 16);
      w1.y = (unsigned)pb[1][2] | ((unsigned)pb[1][3] << 16);
      *reinterpret_cast<uint2*>(&P[(jt * 16 + l15) * PST + 0 * 16 + lg * 4]) = w0;
      *reinterpret_cast<uint2*>(&P[(jt * 16 + l15) * PST + 1 * 16 + lg * 4]) = w1;
    } else {
      uint2 w2, w3;
      w2.x = (unsigned)pb[2][0] | ((unsigned)pb[2][1] << 16);
      w2.y = (unsigned)pb[2][2] | ((unsigned)pb[2][3] << 16);
      w3.x = (unsigned)pb[3][0] | ((unsigned)pb[3][1] << 16);
      w3.y = (unsigned)pb[3][2] | ((unsigned)pb[3][3] << 16);
      *reinterpret_cast<uint2*>(&P[(jt * 16 + l15) * PST + 2 * 16 + lg * 4]) = w2;
      *reinterpret_cast<uint2*>(&P[(jt * 16 + l15) * PST + 3 * 16 + lg * 4]) = w3;
    }
    if (wid < 4 && lane < 16) scl_lds[jt * 16 + lane] = scale;
    __syncthreads();

    // ---- conditional rescale of O by per-j scale ----
    float sc[4];
    #pragma unroll
    for (int jj = 0; jj < 4; ++jj) sc[jj] = scl_lds[jj * 16 + l15];
    bool need = (sc[0] != 1.f) | (sc[1] != 1.f) | (sc[2] != 1.f) | (sc[3] != 1.f);
    if (__any(need)) {
      #pragma unroll
      for (int ct = 0; ct < 4; ++ct)
        #pragma unroll
        for (int jj = 0; jj < 4; ++jj)
          #pragma unroll
          for (int r = 0; r < 4; ++r) O[ct][jj][r] *= sc[jj];
    }

    // ---- PV: O[c,j] += V[c,i] P[i,j] ----
    #pragma unroll
    for (int is = 0; is < 2; ++is) {
      short8 pf[4];
      #pragma unroll
      for (int jj = 0; jj < 4; ++jj)
        pf[jj] = *reinterpret_cast<const short8*>(&P[(jj * 16 + l15) * PST + is * 32 + lg * 8]);
      #pragma unroll
      for (int ct = 0; ct < 4; ++ct)
        #pragma unroll
        for (int jj = 0; jj < 4; ++jj)
          O[ct][jj] = __builtin_amdgcn_mfma_f32_16x16x32_bf16(vf[is][ct], pf[jj], O[ct][jj], 0, 0, 0);
    }
    __syncthreads();
  }

  if (wid < 4 && lane < 16) lsum_lds[jt * 16 + lane] = lsum;
  __syncthreads();
  const float gamma = *gamma_p;
  #pragma unroll
  for (int jj = 0; jj < 4; ++jj) {
    float linv = gamma / lsum_lds[jj * 16 + l15];
    int j = j0 + jj * 16 + l15;
    #pragma unroll
    for (int ct = 0; ct < 4; ++ct) {
      #pragma unroll
      for (int r = 0; r < 4; ++r) {
        int c = c0 + ct * 16 + lg * 4 + r;
        size_t idx = (size_t)(b * Cc + c) * Tc + j;
        out[idx] = v[idx] + linv * O[ct][jj][r];
      }
    }
  }
}

extern "C" void kernel_launch(void* const* d_in, const int* in_sizes, int n_in,
                              void* d_out, int out_size, void* d_ws, size_t ws_size,
                              hipStream_t stream) {
  const float* v  = (const float*)d_in[0];
  const float* Wk = (const float*)d_in[1];
  const float* bk = (const float*)d_in[2];
  const float* Wq = (const float*)d_in[3];
  const float* bq = (const float*)d_in[4];
  const float* gm = (const float*)d_in[5];
  float* out = (float*)d_out;

  char* ws = (char*)d_ws;
  u16*   kqb = (u16*)ws;                                   //  8,388,608 B
  u16*   vbf = (u16*)(ws + 8388608);                       // 33,554,432 B
  u16*   Wbf = (u16*)(ws + 8388608 + 33554432);            //    131,072 B
  float* bkq = (float*)(ws + 8388608 + 33554432 + 131072); //        512 B

  prep_kernel<<<dim3(64), dim3(256), 0, stream>>>(Wk, Wq, bk, bq, Wbf, bkq);
  kqv_kernel<<<dim3(Tc / 64, Bc), dim3(256), 0, stream>>>(v, Wbf, bkq, kqb, vbf);
  attn_kernel<<<dim3(Tc / QT, Bc), dim3(512), 0, stream>>>(v, vbf, kqb, gm, out);
}

// Round 3
// 194.640 us; speedup vs baseline: 3.5374x; 1.6722x over previous
//
#include <hip/hip_runtime.h>

#define Bc 16
#define Cc 512
#define Tc 2048
#define QT 128
#define KT 64
#define PST 72   // P_lds row stride (ushort), 64+8 pad
#define LTS 66   // kqv LDS transposed-tile row stride (ushort), 64+2 pad

typedef __attribute__((ext_vector_type(8))) short short8;
typedef __attribute__((ext_vector_type(4))) float f32x4;
typedef unsigned short u16;

static __device__ __forceinline__ u16 f2bf(float x) {
  unsigned u = __float_as_uint(x);
  u += 0x7FFF + ((u >> 16) & 1);   // RNE
  return (u16)(u >> 16);
}

// ---------------- Kernel 0: W -> bf16 (fused k||q), bias -> bkq ----------------
__global__ __launch_bounds__(256) void prep_kernel(
    const float* __restrict__ Wk, const float* __restrict__ Wq,
    const float* __restrict__ bk, const float* __restrict__ bq,
    u16* __restrict__ Wbf, float* __restrict__ bkq)
{
  int idx  = blockIdx.x * 256 + threadIdx.x;
  int base = idx * 4;
  if (base < 128 * Cc) {
    int ch = base >> 9;
    int c  = base & (Cc - 1);
    const float* src = (ch < 64) ? (Wk + (size_t)ch * Cc + c)
                                 : (Wq + (size_t)(ch - 64) * Cc + c);
    f32x4 w = *reinterpret_cast<const f32x4*>(src);
    uint2 o;
    o.x = (unsigned)f2bf(w[0]) | ((unsigned)f2bf(w[1]) << 16);
    o.y = (unsigned)f2bf(w[2]) | ((unsigned)f2bf(w[3]) << 16);
    *reinterpret_cast<uint2*>(Wbf + base) = o;
  }
  if (idx < 128) bkq[idx] = (idx < 64) ? bk[idx] : bq[idx - 64];
}

// ---------------- Kernel 1: kq[t][ch] via MFMA + vbf16 emission ----------------
__global__ __launch_bounds__(256) void kqv_kernel(
    const float* __restrict__ v, const u16* __restrict__ Wbf,
    const float* __restrict__ bkq, u16* __restrict__ kq, u16* __restrict__ vbf)
{
  __shared__ u16 LDSt[64][LTS];   // [t][c] transposed bf16 tile
  const int b   = blockIdx.y;
  const int t0  = blockIdx.x * 64;
  const int tid = threadIdx.x;
  const int lane = tid & 63;
  const int w    = tid >> 6;     // 0..3
  const int l15  = lane & 15;
  const int lg   = lane >> 4;

  f32x4 acc[8];
  #pragma unroll
  for (int mt = 0; mt < 8; ++mt) acc[mt] = f32x4{0.f, 0.f, 0.f, 0.f};

  const float* vb = v + (size_t)b * Cc * Tc + t0;
  float x[16];
  #pragma unroll
  for (int r = 0; r < 16; ++r) x[r] = vb[(size_t)(w * 16 + r) * Tc + lane];

  for (int c0 = 0; c0 < Cc; c0 += 64) {
    __syncthreads();
    #pragma unroll
    for (int r = 0; r < 16; ++r) {
      u16 hb = f2bf(x[r]);
      LDSt[lane][w * 16 + r] = hb;
      vbf[((size_t)b * Cc + c0 + w * 16 + r) * Tc + t0 + lane] = hb;
    }
    __syncthreads();
    if (c0 + 64 < Cc) {
      #pragma unroll
      for (int r = 0; r < 16; ++r)
        x[r] = vb[(size_t)(c0 + 64 + w * 16 + r) * Tc + lane];
    }
    #pragma unroll
    for (int ks = 0; ks < 2; ++ks) {
      short8 bfrag = *reinterpret_cast<const short8*>(&LDSt[w * 16 + l15][ks * 32 + lg * 8]);
      #pragma unroll
      for (int mt = 0; mt < 8; ++mt) {
        short8 afrag = *reinterpret_cast<const short8*>(
            Wbf + (size_t)(mt * 16 + l15) * Cc + c0 + ks * 32 + lg * 8);
        acc[mt] = __builtin_amdgcn_mfma_f32_16x16x32_bf16(afrag, bfrag, acc[mt], 0, 0, 0);
      }
    }
  }
  const int t = t0 + w * 16 + l15;
  u16* op = kq + ((size_t)b * Tc + t) * 128;
  #pragma unroll
  for (int mt = 0; mt < 8; ++mt) {
    int chb = mt * 16 + lg * 4;
    float a0 = acc[mt][0] + bkq[chb + 0];
    float a1 = acc[mt][1] + bkq[chb + 1];
    float a2 = acc[mt][2] + bkq[chb + 2];
    float a3 = acc[mt][3] + bkq[chb + 3];
    uint2 o;
    o.x = (unsigned)f2bf(a0) | ((unsigned)f2bf(a1) << 16);
    o.y = (unsigned)f2bf(a2) | ((unsigned)f2bf(a3) << 16);
    *reinterpret_cast<uint2*>(op + chb) = o;
  }
}

// ---------------- Kernel 2: flash attention over i ----------------
// QT=128, 8 waves; wave owns j-tile jt=wid (S + softmax) and channel slice c0=wid*64 (O).
__global__ __launch_bounds__(512, 2) void attn_kernel(
    const float* __restrict__ v, const u16* __restrict__ vbf,
    const u16* __restrict__ kq, const float* __restrict__ gamma_p,
    float* __restrict__ out)
{
  __shared__ u16 P[2][QT * PST];
  __shared__ float scl_lds[2][QT];
  __shared__ float lsum_lds[QT];

  // XCD-aware swizzle: 256 blocks, 8 XCDs -> each XCD gets 2 consecutive b's
  const int L   = blockIdx.x;
  const int lin = (L & 7) * 32 + (L >> 3);
  const int b   = lin >> 4;
  const int j0  = (lin & 15) * QT;
  const int tid = threadIdx.x;
  const int lane = tid & 63;
  const int wid  = tid >> 6;      // 0..7 = owned j-tile AND channel slice
  const int l15  = lane & 15;
  const int lg   = lane >> 4;     // 0..3
  const int c0   = wid * 64;

  // Q B-fragments for owned j-tile
  short8 qf0, qf1;
  {
    const u16* qp = kq + (size_t)(b * Tc + j0 + wid * 16 + l15) * 128 + 64 + lg * 8;
    qf0 = *reinterpret_cast<const short8*>(qp);
    qf1 = *reinterpret_cast<const short8*>(qp + 32);
  }

  f32x4 O[4][8];   // [ct][jj]
  #pragma unroll
  for (int a = 0; a < 4; ++a)
    #pragma unroll
    for (int bb = 0; bb < 8; ++bb) O[a][bb] = f32x4{0.f, 0.f, 0.f, 0.f};

  float m = -1e30f, lsum = 0.f;

  const u16* kbase = kq + (size_t)b * Tc * 128 + lg * 8;
  const u16* vbase = vbf + ((size_t)b * Cc + c0) * Tc;

  short8 kf[4][2];   // K frags, prefetched one i-tile ahead
  short8 vf[2][4];   // V frags, prefetched one i-tile ahead
  #pragma unroll
  for (int it = 0; it < 4; ++it) {
    const u16* kp = kbase + (size_t)(it * 16 + l15) * 128;
    kf[it][0] = *reinterpret_cast<const short8*>(kp);
    kf[it][1] = *reinterpret_cast<const short8*>(kp + 32);
  }
  #pragma unroll
  for (int is = 0; is < 2; ++is)
    #pragma unroll
    for (int ct = 0; ct < 4; ++ct)
      vf[is][ct] = *reinterpret_cast<const short8*>(
          vbase + (size_t)(ct * 16 + l15) * Tc + is * 32 + lg * 8);

  int pb = 0;
  for (int i0 = 0; i0 < Tc; i0 += KT, pb ^= 1) {
    // ---- S tile from prefetched K ----
    f32x4 sacc[4];
    #pragma unroll
    for (int it = 0; it < 4; ++it) {
      f32x4 s = f32x4{0.f, 0.f, 0.f, 0.f};
      s = __builtin_amdgcn_mfma_f32_16x16x32_bf16(kf[it][0], qf0, s, 0, 0, 0);
      s = __builtin_amdgcn_mfma_f32_16x16x32_bf16(kf[it][1], qf1, s, 0, 0, 0);
      sacc[it] = s;
    }
    // ---- prefetch next K tile (covered by softmax+barrier+PV) ----
    if (i0 + KT < Tc) {
      #pragma unroll
      for (int it = 0; it < 4; ++it) {
        const u16* kp = kbase + (size_t)(i0 + KT + it * 16 + l15) * 128;
        kf[it][0] = *reinterpret_cast<const short8*>(kp);
        kf[it][1] = *reinterpret_cast<const short8*>(kp + 32);
      }
    }

    // ---- online softmax over i (defer-max THR=8) ----
    float tmax = -1e30f;
    #pragma unroll
    for (int it = 0; it < 4; ++it)
      #pragma unroll
      for (int r = 0; r < 4; ++r) tmax = fmaxf(tmax, sacc[it][r]);
    tmax = fmaxf(tmax, __shfl_xor(tmax, 16));
    tmax = fmaxf(tmax, __shfl_xor(tmax, 32));
    bool defer  = (tmax - m <= 8.f);
    float mnew  = defer ? m : tmax;
    float scale = defer ? 1.f : __expf(m - tmax);
    float psum = 0.f;
    u16 pbv[4][4];
    #pragma unroll
    for (int it = 0; it < 4; ++it)
      #pragma unroll
      for (int r = 0; r < 4; ++r) {
        float p = __expf(sacc[it][r] - mnew);
        psum += p;
        pbv[it][r] = f2bf(p);
      }
    psum += __shfl_xor(psum, 16);
    psum += __shfl_xor(psum, 32);
    lsum = lsum * scale + psum;
    m = mnew;

    // ---- write own P rows [j = wid*16+l15][i] ----
    {
      u16* prow = &P[pb][(wid * 16 + l15) * PST];
      #pragma unroll
      for (int it = 0; it < 4; ++it) {
        uint2 wv;
        wv.x = (unsigned)pbv[it][0] | ((unsigned)pbv[it][1] << 16);
        wv.y = (unsigned)pbv[it][2] | ((unsigned)pbv[it][3] << 16);
        *reinterpret_cast<uint2*>(prow + it * 16 + lg * 4) = wv;
      }
    }
    if (lane < 16) scl_lds[pb][wid * 16 + lane] = scale;
    __syncthreads();   // single barrier per i-tile (P double-buffered)

    // ---- conditional rescale of O ----
    float sc[8];
    #pragma unroll
    for (int jj = 0; jj < 8; ++jj) sc[jj] = scl_lds[pb][jj * 16 + l15];
    bool need = false;
    #pragma unroll
    for (int jj = 0; jj < 8; ++jj) need |= (sc[jj] != 1.f);
    if (__any(need)) {
      #pragma unroll
      for (int ct = 0; ct < 4; ++ct)
        #pragma unroll
        for (int jj = 0; jj < 8; ++jj)
          #pragma unroll
          for (int r = 0; r < 4; ++r) O[ct][jj][r] *= sc[jj];
    }

    // ---- PV: O[c,j] += V[c,i] P[i,j] ----
    __builtin_amdgcn_s_setprio(1);
    #pragma unroll
    for (int is = 0; is < 2; ++is) {
      short8 pf[8];
      #pragma unroll
      for (int jj = 0; jj < 8; ++jj)
        pf[jj] = *reinterpret_cast<const short8*>(
            &P[pb][(jj * 16 + l15) * PST + is * 32 + lg * 8]);
      #pragma unroll
      for (int ct = 0; ct < 4; ++ct)
        #pragma unroll
        for (int jj = 0; jj < 8; ++jj)
          O[ct][jj] = __builtin_amdgcn_mfma_f32_16x16x32_bf16(vf[is][ct], pf[jj], O[ct][jj], 0, 0, 0);
    }
    __builtin_amdgcn_s_setprio(0);

    // ---- prefetch next V tile (covered by next S+softmax+barrier) ----
    if (i0 + KT < Tc) {
      #pragma unroll
      for (int is = 0; is < 2; ++is)
        #pragma unroll
        for (int ct = 0; ct < 4; ++ct)
          vf[is][ct] = *reinterpret_cast<const short8*>(
              vbase + (size_t)(ct * 16 + l15) * Tc + (i0 + KT) + is * 32 + lg * 8);
    }
  }

  if (lane < 16) lsum_lds[wid * 16 + lane] = lsum;
  __syncthreads();
  const float gamma = *gamma_p;
  #pragma unroll
  for (int jj = 0; jj < 8; ++jj) {
    float linv = gamma / lsum_lds[jj * 16 + l15];
    int j = j0 + jj * 16 + l15;
    #pragma unroll
    for (int ct = 0; ct < 4; ++ct) {
      #pragma unroll
      for (int r = 0; r < 4; ++r) {
        int c = c0 + ct * 16 + lg * 4 + r;
        size_t idx = (size_t)(b * Cc + c) * Tc + j;
        out[idx] = v[idx] + linv * O[ct][jj][r];
      }
    }
  }
}

extern "C" void kernel_launch(void* const* d_in, const int* in_sizes, int n_in,
                              void* d_out, int out_size, void* d_ws, size_t ws_size,
                              hipStream_t stream) {
  const float* v  = (const float*)d_in[0];
  const float* Wk = (const float*)d_in[1];
  const float* bk = (const float*)d_in[2];
  const float* Wq = (const float*)d_in[3];
  const float* bq = (const float*)d_in[4];
  const float* gm = (const float*)d_in[5];
  float* out = (float*)d_out;

  char* ws = (char*)d_ws;
  u16*   kqb = (u16*)ws;                                   //  8,388,608 B
  u16*   vbf = (u16*)(ws + 8388608);                       // 33,554,432 B
  u16*   Wbf = (u16*)(ws + 8388608 + 33554432);            //    131,072 B
  float* bkq = (float*)(ws + 8388608 + 33554432 + 131072); //        512 B

  prep_kernel<<<dim3(64), dim3(256), 0, stream>>>(Wk, Wq, bk, bq, Wbf, bkq);
  kqv_kernel<<<dim3(Tc / 64, Bc), dim3(256), 0, stream>>>(v, Wbf, bkq, kqb, vbf);
  attn_kernel<<<dim3((Tc / QT) * Bc), dim3(512), 0, stream>>>(v, vbf, kqb, gm, out);
}